// Round 1
// baseline (812.137 us; speedup 1.0000x reference)
//
#include <hip/hip_runtime.h>
#include <math.h>

#define IN_DIM 256
#define HID 64
#define OUT_DIM 40
#define EPS_RES 0.3f

// ---------------------------------------------------------------- degree
__global__ void k_deg(const int* __restrict__ dst, int* __restrict__ deg, int E) {
    int i = blockIdx.x * blockDim.x + threadIdx.x;
    if (i < E) atomicAdd(&deg[dst[i]], 1);
}

__global__ void k_dinv(const int* __restrict__ deg, float* __restrict__ dinv, int N) {
    int i = blockIdx.x * blockDim.x + threadIdx.x;
    if (i < N) {
        float v = (float)deg[i];
        dinv[i] = rsqrtf(fmaxf(v, 1.0f));
    }
}

// ------------------------------------------------- x0 = relu(h @ W1^T + b1)
// thread-per-row; h read as 8x float4 = one full 128B line per lane per k-batch
// (exact 51.2MB HBM traffic); W1 indices are wave-uniform -> scalar loads.
__global__ __launch_bounds__(256) void k_gemm1(
    const float* __restrict__ h, const float* __restrict__ w,
    const float* __restrict__ b, float* __restrict__ out, int N) {
    int r = blockIdx.x * 256 + threadIdx.x;
    if (r >= N) return;
    const float4* hr = (const float4*)(h + (size_t)r * IN_DIM);
    float acc[HID];
#pragma unroll
    for (int j = 0; j < HID; ++j) acc[j] = b[j];
#pragma unroll 1
    for (int kb = 0; kb < IN_DIM / 32; ++kb) {
        float4 hv[8];
#pragma unroll
        for (int m = 0; m < 8; ++m) hv[m] = hr[kb * 8 + m];
#pragma unroll
        for (int m = 0; m < 8; ++m) {
            float c0 = hv[m].x, c1 = hv[m].y, c2 = hv[m].z, c3 = hv[m].w;
            int k = kb * 32 + m * 4;
#pragma unroll
            for (int j = 0; j < HID; ++j) {
                acc[j] = fmaf(c0, w[j * IN_DIM + k + 0], acc[j]);
                acc[j] = fmaf(c1, w[j * IN_DIM + k + 1], acc[j]);
                acc[j] = fmaf(c2, w[j * IN_DIM + k + 2], acc[j]);
                acc[j] = fmaf(c3, w[j * IN_DIM + k + 3], acc[j]);
            }
        }
    }
    float4* o = (float4*)(out + (size_t)r * HID);
#pragma unroll
    for (int q = 0; q < HID / 4; ++q) {
        float4 v;
        v.x = fmaxf(acc[q * 4 + 0], 0.f);
        v.y = fmaxf(acc[q * 4 + 1], 0.f);
        v.z = fmaxf(acc[q * 4 + 2], 0.f);
        v.w = fmaxf(acc[q * 4 + 3], 0.f);
        o[q] = v;
    }
}

// --------------------------------------------- per-node gate proj + z init
// ga[n] = x[n] . gw[0:64]   (dst role)
// gb[n] = x[n] . gw[64:128] (src role)
// z[n]  = EPS * raw[n]      (residual folded into scatter target)
__global__ __launch_bounds__(256) void k_layer_pre(
    const float* __restrict__ x, const float* __restrict__ raw,
    const float* __restrict__ gw,
    float* __restrict__ ga, float* __restrict__ gb,
    float* __restrict__ z, int N) {
    int n = blockIdx.x * blockDim.x + threadIdx.x;
    if (n >= N) return;
    const float4* xr = (const float4*)(x + (size_t)n * HID);
    const float4* rr = (const float4*)(raw + (size_t)n * HID);
    float4* zr = (float4*)(z + (size_t)n * HID);
    float a = 0.f, bsum = 0.f;
#pragma unroll
    for (int q = 0; q < HID / 4; ++q) {
        float4 v = xr[q];
        a    += v.x * gw[q * 4 + 0] + v.y * gw[q * 4 + 1]
              + v.z * gw[q * 4 + 2] + v.w * gw[q * 4 + 3];
        bsum += v.x * gw[HID + q * 4 + 0] + v.y * gw[HID + q * 4 + 1]
              + v.z * gw[HID + q * 4 + 2] + v.w * gw[HID + q * 4 + 3];
        float4 rv = rr[q];
        zr[q] = make_float4(EPS_RES * rv.x, EPS_RES * rv.y,
                            EPS_RES * rv.z, EPS_RES * rv.w);
    }
    ga[n] = a;
    gb[n] = bsum;
}

// -------------------------------------------------- edge scatter (1 wave/edge)
// e = tanh(ga[dst] + gb[src] + bias) * d[dst] * d[src]
// z[dst][k] += x[src][k] * e   (64 coalesced float atomics per edge)
__global__ __launch_bounds__(256) void k_edge_scatter(
    const int* __restrict__ src, const int* __restrict__ dst,
    const float* __restrict__ ga, const float* __restrict__ gb,
    const float* __restrict__ dinv, const float* __restrict__ x,
    const float* __restrict__ gbias, float* __restrict__ z, int E) {
    int wid = blockIdx.x * 4 + (threadIdx.x >> 6);
    int lane = threadIdx.x & 63;
    if (wid >= E) return;
    int s = src[wid];
    int t = dst[wid];
    float g = tanhf(ga[t] + gb[s] + gbias[0]);
    float e = g * dinv[t] * dinv[s];
    float xv = x[(size_t)s * HID + lane];
    atomicAdd(&z[(size_t)t * HID + lane], xv * e);
}

// ------------------------------------- logits = x @ W2^T + b2, log_softmax
// fully unrolled so xv[]/acc[] stay in registers (no scratch), W2 scalar loads
__global__ __launch_bounds__(256) void k_head(
    const float* __restrict__ x, const float* __restrict__ w2,
    const float* __restrict__ b2, float* __restrict__ out, int N) {
    int n = blockIdx.x * 256 + threadIdx.x;
    if (n >= N) return;
    const float4* xr = (const float4*)(x + (size_t)n * HID);
    float xv[HID];
#pragma unroll
    for (int q = 0; q < HID / 4; ++q) {
        float4 v = xr[q];
        xv[q * 4 + 0] = v.x; xv[q * 4 + 1] = v.y;
        xv[q * 4 + 2] = v.z; xv[q * 4 + 3] = v.w;
    }
    float acc[OUT_DIM];
#pragma unroll
    for (int j = 0; j < OUT_DIM; ++j) acc[j] = b2[j];
#pragma unroll
    for (int k = 0; k < HID; ++k) {
        float c = xv[k];
#pragma unroll
        for (int j = 0; j < OUT_DIM; ++j)
            acc[j] = fmaf(c, w2[j * HID + k], acc[j]);
    }
    float m = acc[0];
#pragma unroll
    for (int j = 1; j < OUT_DIM; ++j) m = fmaxf(m, acc[j]);
    float ssum = 0.f;
#pragma unroll
    for (int j = 0; j < OUT_DIM; ++j) ssum += expf(acc[j] - m);
    float lse = m + logf(ssum);
    float* o = out + (size_t)n * OUT_DIM;
#pragma unroll
    for (int j = 0; j < OUT_DIM; ++j) o[j] = acc[j] - lse;
}

// ----------------------------------------------------------------- launcher
extern "C" void kernel_launch(void* const* d_in, const int* in_sizes, int n_in,
                              void* d_out, int out_size, void* d_ws, size_t ws_size,
                              hipStream_t stream) {
    const float* h    = (const float*)d_in[0];
    const int*   src  = (const int*)d_in[1];
    const int*   dst  = (const int*)d_in[2];
    const float* t1_w = (const float*)d_in[3];
    const float* t1_b = (const float*)d_in[4];
    const float* gw1  = (const float*)d_in[5];
    const float* gb1  = (const float*)d_in[6];
    const float* gw2  = (const float*)d_in[7];
    const float* gb2  = (const float*)d_in[8];
    const float* t2_w = (const float*)d_in[9];
    const float* t2_b = (const float*)d_in[10];
    float* out = (float*)d_out;

    const int N = in_sizes[0] / IN_DIM;
    const int E = in_sizes[1];

    // workspace layout (floats): raw | xA | xB | dinv | ga | gb | deg(int)
    float* ws   = (float*)d_ws;
    float* raw  = ws;
    float* xA   = raw + (size_t)N * HID;
    float* xB   = xA + (size_t)N * HID;
    float* dinv = xB + (size_t)N * HID;
    float* ga   = dinv + N;
    float* gb   = ga + N;
    int*   deg  = (int*)(gb + N);

    const int TB = 256;
    hipMemsetAsync(deg, 0, (size_t)N * sizeof(int), stream);
    k_deg<<<(E + TB - 1) / TB, TB, 0, stream>>>(dst, deg, E);
    k_dinv<<<(N + TB - 1) / TB, TB, 0, stream>>>(deg, dinv, N);
    k_gemm1<<<(N + TB - 1) / TB, TB, 0, stream>>>(h, t1_w, t1_b, raw, N);

    // layer 1: x = raw -> xA
    k_layer_pre<<<(N + TB - 1) / TB, TB, 0, stream>>>(raw, raw, gw1, ga, gb, xA, N);
    k_edge_scatter<<<(E + 3) / 4, TB, 0, stream>>>(src, dst, ga, gb, dinv, raw, gb1, xA, E);

    // layer 2: x = xA -> xB
    k_layer_pre<<<(N + TB - 1) / TB, TB, 0, stream>>>(xA, raw, gw2, ga, gb, xB, N);
    k_edge_scatter<<<(E + 3) / 4, TB, 0, stream>>>(src, dst, ga, gb, dinv, xA, gb2, xB, E);

    k_head<<<(N + TB - 1) / TB, TB, 0, stream>>>(xB, t2_w, t2_b, out, N);
}

// Round 2
// 323.881 us; speedup vs baseline: 2.5075x; 2.5075x over previous
//
#include <hip/hip_runtime.h>
#include <math.h>

#define IN_DIM 256
#define HID 64
#define OUT_DIM 40
#define EPS_RES 0.3f
#define SCAN_BLK 256

// ---------------------------------------------------------------- degree
__global__ void k_deg(const int* __restrict__ dst, int* __restrict__ deg, int E) {
    int i = blockIdx.x * blockDim.x + threadIdx.x;
    if (i < E) atomicAdd(&deg[dst[i]], 1);
}

__global__ void k_dinv(const int* __restrict__ deg, float* __restrict__ dinv, int N) {
    int i = blockIdx.x * blockDim.x + threadIdx.x;
    if (i < N) dinv[i] = rsqrtf(fmaxf((float)deg[i], 1.0f));
}

// ------------------------------------------------------- CSR build: scan
__global__ void k_scan_block(const int* __restrict__ deg, int* __restrict__ incl,
                             int* __restrict__ bsum, int N) {
    __shared__ int sm[SCAN_BLK];
    int tid = threadIdx.x;
    int i = blockIdx.x * SCAN_BLK + tid;
    sm[tid] = (i < N) ? deg[i] : 0;
    __syncthreads();
    for (int off = 1; off < SCAN_BLK; off <<= 1) {
        int t = (tid >= off) ? sm[tid - off] : 0;
        __syncthreads();
        sm[tid] += t;
        __syncthreads();
    }
    if (i < N) incl[i] = sm[tid];
    if (tid == SCAN_BLK - 1) bsum[blockIdx.x] = sm[tid];
}

// NB <= 256 (N <= 65536)
__global__ void k_scan_tops(const int* __restrict__ bsum, int* __restrict__ boff, int NB) {
    __shared__ int sm[SCAN_BLK];
    int tid = threadIdx.x;
    int v = (tid < NB) ? bsum[tid] : 0;
    sm[tid] = v;
    __syncthreads();
    for (int off = 1; off < SCAN_BLK; off <<= 1) {
        int t = (tid >= off) ? sm[tid - off] : 0;
        __syncthreads();
        sm[tid] += t;
        __syncthreads();
    }
    if (tid < NB) boff[tid] = sm[tid] - v;  // exclusive block offsets
}

__global__ void k_scan_add(const int* __restrict__ incl, const int* __restrict__ boff,
                           const int* __restrict__ deg, int* __restrict__ rowp,
                           int* __restrict__ cursor, int N) {
    int i = blockIdx.x * SCAN_BLK + threadIdx.x;
    if (i >= N) return;
    int inc = incl[i] + boff[blockIdx.x];
    rowp[i + 1] = inc;
    cursor[i] = inc - deg[i];  // exclusive start
    if (i == 0) rowp[0] = 0;
}

__global__ void k_place(const int* __restrict__ src, const int* __restrict__ dst,
                        int* __restrict__ cursor, int* __restrict__ ssrc,
                        int* __restrict__ sdst, int E) {
    int i = blockIdx.x * blockDim.x + threadIdx.x;
    if (i >= E) return;
    int t = dst[i];
    int p = atomicAdd(&cursor[t], 1);
    ssrc[p] = src[i];
    sdst[p] = t;
}

// ------------------------------------------------- x0 = relu(h @ W1^T + b1)
// 4 waves/block: wave w -> cols [16w,16w+16), lane -> row. W1/bias wave-uniform
// (readfirstlane) -> scalar loads; acc[16] stays in VGPRs (no spill).
__global__ __launch_bounds__(256) void k_gemm1(
    const float* __restrict__ h, const float* __restrict__ w,
    const float* __restrict__ b, float* __restrict__ out, int N) {
    int lane = threadIdx.x & 63;
    int c0 = __builtin_amdgcn_readfirstlane(threadIdx.x >> 6) * 16;
    int row = blockIdx.x * 64 + lane;
    if (row >= N) return;
    const float4* hr = (const float4*)(h + (size_t)row * IN_DIM);
    float acc[16];
#pragma unroll
    for (int j = 0; j < 16; ++j) acc[j] = b[c0 + j];
#pragma unroll 4
    for (int kb = 0; kb < IN_DIM / 4; ++kb) {
        float4 hv = hr[kb];
#pragma unroll
        for (int j = 0; j < 16; ++j) {
            const float* wr = w + (size_t)(c0 + j) * IN_DIM + kb * 4;
            acc[j] = fmaf(hv.x, wr[0], acc[j]);
            acc[j] = fmaf(hv.y, wr[1], acc[j]);
            acc[j] = fmaf(hv.z, wr[2], acc[j]);
            acc[j] = fmaf(hv.w, wr[3], acc[j]);
        }
    }
    float4* o = (float4*)(out + (size_t)row * HID + c0);
#pragma unroll
    for (int q = 0; q < 4; ++q) {
        float4 v;
        v.x = fmaxf(acc[q * 4 + 0], 0.f);
        v.y = fmaxf(acc[q * 4 + 1], 0.f);
        v.z = fmaxf(acc[q * 4 + 2], 0.f);
        v.w = fmaxf(acc[q * 4 + 3], 0.f);
        o[q] = v;
    }
}

// --------------------------------------------------- per-node gate proj
__global__ __launch_bounds__(256) void k_gatepre(
    const float* __restrict__ x, const float* __restrict__ gw,
    float* __restrict__ ga, float* __restrict__ gb, int N) {
    int n = blockIdx.x * blockDim.x + threadIdx.x;
    if (n >= N) return;
    const float4* xr = (const float4*)(x + (size_t)n * HID);
    float a = 0.f, bsum = 0.f;
#pragma unroll
    for (int q = 0; q < HID / 4; ++q) {
        float4 v = xr[q];
        a    += v.x * gw[q * 4 + 0] + v.y * gw[q * 4 + 1]
              + v.z * gw[q * 4 + 2] + v.w * gw[q * 4 + 3];
        bsum += v.x * gw[HID + q * 4 + 0] + v.y * gw[HID + q * 4 + 1]
              + v.z * gw[HID + q * 4 + 2] + v.w * gw[HID + q * 4 + 3];
    }
    ga[n] = a;
    gb[n] = bsum;
}

// ------------------------------------------- per-edge coefficient (sorted)
__global__ void k_edge_e(const int* __restrict__ ssrc, const int* __restrict__ sdst,
                         const float* __restrict__ ga, const float* __restrict__ gb,
                         const float* __restrict__ dinv, const float* __restrict__ gbias,
                         float* __restrict__ e, int E) {
    int i = blockIdx.x * blockDim.x + threadIdx.x;
    if (i >= E) return;
    int s = ssrc[i], t = sdst[i];
    float g = tanhf(ga[t] + gb[s] + gbias[0]);
    e[i] = g * dinv[t] * dinv[s];
}

// ------------------------------------- gather: z[t] = EPS*raw[t] + sum e*x[s]
// one wave per node, lane = hid dim; edge metadata wave-uniform -> scalar loads
__global__ __launch_bounds__(256) void k_gather(
    const int* __restrict__ rowp, const int* __restrict__ ssrc,
    const float* __restrict__ e, const float* __restrict__ x,
    const float* __restrict__ raw, float* __restrict__ z, int N) {
    int lane = threadIdx.x & 63;
    int wv = __builtin_amdgcn_readfirstlane(threadIdx.x >> 6);
    int t = blockIdx.x * 4 + wv;
    if (t >= N) return;
    float acc = EPS_RES * raw[(size_t)t * HID + lane];
    int k = rowp[t];
    int end = rowp[t + 1];
    for (; k + 2 <= end; k += 2) {
        int s0 = ssrc[k], s1 = ssrc[k + 1];
        float e0 = e[k], e1 = e[k + 1];
        float x0 = x[(size_t)s0 * HID + lane];
        float x1 = x[(size_t)s1 * HID + lane];
        acc = fmaf(e0, x0, acc);
        acc = fmaf(e1, x1, acc);
    }
    if (k < end)
        acc = fmaf(e[k], x[(size_t)ssrc[k] * HID + lane], acc);
    z[(size_t)t * HID + lane] = acc;
}

// ------------------------------------- logits = x @ W2^T + b2, log_softmax
__global__ __launch_bounds__(256) void k_head(
    const float* __restrict__ x, const float* __restrict__ w2,
    const float* __restrict__ b2, float* __restrict__ out, int N) {
    int n = blockIdx.x * 256 + threadIdx.x;
    if (n >= N) return;
    const float4* xr = (const float4*)(x + (size_t)n * HID);
    float acc[OUT_DIM];
#pragma unroll
    for (int j = 0; j < OUT_DIM; ++j) acc[j] = b2[j];
#pragma unroll 2
    for (int kb = 0; kb < HID / 4; ++kb) {
        float4 v = xr[kb];
#pragma unroll
        for (int j = 0; j < OUT_DIM; ++j) {
            const float* wr = w2 + (size_t)j * HID + kb * 4;
            acc[j] = fmaf(v.x, wr[0], acc[j]);
            acc[j] = fmaf(v.y, wr[1], acc[j]);
            acc[j] = fmaf(v.z, wr[2], acc[j]);
            acc[j] = fmaf(v.w, wr[3], acc[j]);
        }
    }
    float m = acc[0];
#pragma unroll
    for (int j = 1; j < OUT_DIM; ++j) m = fmaxf(m, acc[j]);
    float ssum = 0.f;
#pragma unroll
    for (int j = 0; j < OUT_DIM; ++j) ssum += expf(acc[j] - m);
    float lse = m + logf(ssum);
    float* o = out + (size_t)n * OUT_DIM;
#pragma unroll
    for (int j = 0; j < OUT_DIM; ++j) o[j] = acc[j] - lse;
}

// ----------------------------------------------------------------- launcher
extern "C" void kernel_launch(void* const* d_in, const int* in_sizes, int n_in,
                              void* d_out, int out_size, void* d_ws, size_t ws_size,
                              hipStream_t stream) {
    const float* h    = (const float*)d_in[0];
    const int*   src  = (const int*)d_in[1];
    const int*   dst  = (const int*)d_in[2];
    const float* t1_w = (const float*)d_in[3];
    const float* t1_b = (const float*)d_in[4];
    const float* gw1  = (const float*)d_in[5];
    const float* gb1  = (const float*)d_in[6];
    const float* gw2  = (const float*)d_in[7];
    const float* gb2  = (const float*)d_in[8];
    const float* t2_w = (const float*)d_in[9];
    const float* t2_b = (const float*)d_in[10];
    float* out = (float*)d_out;

    const int N = in_sizes[0] / IN_DIM;
    const int E = in_sizes[1];
    const int NB = (N + SCAN_BLK - 1) / SCAN_BLK;

    // workspace layout
    float* ws   = (float*)d_ws;
    float* raw  = ws;                          // N*64
    float* xA   = raw + (size_t)N * HID;       // N*64
    float* xB   = xA + (size_t)N * HID;        // N*64
    float* dinv = xB + (size_t)N * HID;        // N
    float* ga   = dinv + N;                    // N
    float* gbv  = ga + N;                      // N
    float* e_s  = gbv + N;                     // E
    int* deg    = (int*)(e_s + E);             // N
    int* incl   = deg + N;                     // N
    int* rowp   = incl + N;                    // N+1
    int* cursor = rowp + N + 1;                // N
    int* bsum   = cursor + N;                  // NB
    int* boff   = bsum + NB;                   // NB
    int* ssrc   = boff + NB;                   // E
    int* sdst   = ssrc + E;                    // E

    const int TB = 256;
    hipMemsetAsync(deg, 0, (size_t)N * sizeof(int), stream);
    k_deg<<<(E + TB - 1) / TB, TB, 0, stream>>>(dst, deg, E);
    k_dinv<<<NB, TB, 0, stream>>>(deg, dinv, N);
    k_scan_block<<<NB, TB, 0, stream>>>(deg, incl, bsum, N);
    k_scan_tops<<<1, TB, 0, stream>>>(bsum, boff, NB);
    k_scan_add<<<NB, TB, 0, stream>>>(incl, boff, deg, rowp, cursor, N);
    k_place<<<(E + TB - 1) / TB, TB, 0, stream>>>(src, dst, cursor, ssrc, sdst, E);

    k_gemm1<<<(N + 63) / 64, TB, 0, stream>>>(h, t1_w, t1_b, raw, N);

    // layer 1: raw -> xA
    k_gatepre<<<NB, TB, 0, stream>>>(raw, gw1, ga, gbv, N);
    k_edge_e<<<(E + TB - 1) / TB, TB, 0, stream>>>(ssrc, sdst, ga, gbv, dinv, gb1, e_s, E);
    k_gather<<<(N + 3) / 4, TB, 0, stream>>>(rowp, ssrc, e_s, raw, raw, xA, N);

    // layer 2: xA -> xB
    k_gatepre<<<NB, TB, 0, stream>>>(xA, gw2, ga, gbv, N);
    k_edge_e<<<(E + TB - 1) / TB, TB, 0, stream>>>(ssrc, sdst, ga, gbv, dinv, gb2, e_s, E);
    k_gather<<<(N + 3) / 4, TB, 0, stream>>>(rowp, ssrc, e_s, xA, raw, xB, N);

    k_head<<<(N + TB - 1) / TB, TB, 0, stream>>>(xB, t2_w, t2_b, out, N);
}